// Round 5
// baseline (302.735 us; speedup 1.0000x reference)
//
#include <hip/hip_runtime.h>
#include <cstdint>
#include <cstddef>

#define NNODES 10000
#define NEDGES 320000
#define NTOT   (NEDGES + NNODES)
#define NPAD   10048  // 157*64

typedef unsigned short ushort_t;
typedef short bf16x8 __attribute__((ext_vector_type(8)));
typedef float f32x4 __attribute__((ext_vector_type(4)));

__device__ __forceinline__ float lrelu(float x) { return x > 0.f ? x : 0.2f * x; }
__device__ __forceinline__ ushort_t f2b(float v) {
  unsigned b = __float_as_uint(v);
  b += 0x7fffu + ((b >> 16) & 1u);  // RNE
  return (ushort_t)(b >> 16);
}
__device__ __forceinline__ float bcast_f(float v, int lane) {
  return __uint_as_float(__builtin_amdgcn_readlane(__float_as_uint(v), lane));
}
__device__ __forceinline__ int bcast_i(int v, int lane) {
  return __builtin_amdgcn_readlane(v, lane);
}

// ---------- fused prep: x->bf16, W0/W1/W2 -> WT bf16, edge histogram ----------
// counts must be zeroed beforehand (hipMemsetAsync).
#define BX   5000   // 10000*128/256
#define BW0  128    // 128*256/256
#define BW1  256    // 256*256/256
#define BW2  64     // 256*64/256
#define BH   1250   // 320000/256
__global__ __launch_bounds__(256) void prep_kernel(
    const float* __restrict__ x, const float* __restrict__ W0, const float* __restrict__ W1,
    const float* __restrict__ W2, const int* __restrict__ ei,
    ushort_t* __restrict__ xb0, ushort_t* __restrict__ WT0, ushort_t* __restrict__ WT1,
    ushort_t* __restrict__ WT2, int* __restrict__ counts) {
  int b = blockIdx.x;
  int tid = threadIdx.x;
  if (b < BX) { int i = b * 256 + tid; xb0[i] = f2b(x[i]); return; }
  b -= BX;
  if (b < BW0) {  // W0[128,256] -> WT0[256,128]
    int i = b * 256 + tid; int k = i >> 8, m = i & 255;
    WT0[m * 128 + k] = f2b(W0[i]); return;
  }
  b -= BW0;
  if (b < BW1) {  // W1[256,256] -> WT1[256,256]
    int i = b * 256 + tid; int k = i >> 8, m = i & 255;
    WT1[m * 256 + k] = f2b(W1[i]); return;
  }
  b -= BW1;
  if (b < BW2) {  // W2[256,64] -> WT2[64,256]
    int i = b * 256 + tid; int k = i >> 6, m = i & 63;
    WT2[m * 256 + k] = f2b(W2[i]); return;
  }
  b -= BW2;
  { int e = b * 256 + tid; atomicAdd(&counts[ei[NEDGES + e]], 1); }
}

// ---------- LDS scan: counts(+self loop) -> row_ptr, cursor(+1), self-loop srcs ----------
__global__ __launch_bounds__(256) void scan_kernel(
    const int* __restrict__ counts, int* __restrict__ row_ptr,
    int* __restrict__ cursor, int* __restrict__ srcs) {
  __shared__ int lc[NNODES];
  __shared__ int part[256];
  int t = threadIdx.x;
  for (int i = t; i < NNODES; i += 256) lc[i] = counts[i] + 1;  // +1 = self loop
  __syncthreads();
  const int chunk = (NNODES + 255) >> 8;  // 40
  int base = t * chunk;
  int s = 0;
  for (int i = 0; i < chunk; ++i) {
    int idx = base + i;
    if (idx < NNODES) s += lc[idx];
  }
  part[t] = s;
  __syncthreads();
  for (int off = 1; off < 256; off <<= 1) {
    int v = (t >= off) ? part[t - off] : 0;
    __syncthreads();
    part[t] += v;
    __syncthreads();
  }
  int run = part[t] - s;  // exclusive prefix
  for (int i = 0; i < chunk; ++i) {
    int idx = base + i;
    if (idx < NNODES) {
      row_ptr[idx] = run;
      srcs[run] = idx;        // self loop first
      cursor[idx] = run + 1;  // edges land after it
      run += lc[idx];
    }
  }
  if (t == 255) row_ptr[NNODES] = part[255];
}

__global__ void scatter_kernel(const int* __restrict__ ei, int* __restrict__ cursor,
                               int* __restrict__ srcs) {
  int e = blockIdx.x * 256 + threadIdx.x;
  if (e < NEDGES) {
    int s = ei[e], d = ei[NEDGES + e];
    srcs[atomicAdd(&cursor[d], 1)] = s;
  }
}

// ---------- fused MFMA GEMM + attention coefficients ----------
template <int K, int H>
__global__ __launch_bounds__(256) void gemm_att_kernel(
    const ushort_t* __restrict__ Ab,   // [NPAD, K] bf16
    const ushort_t* __restrict__ WT,   // [H*64, K] bf16
    const float* __restrict__ atts, const float* __restrict__ attd,  // [H*64]
    ushort_t* __restrict__ hb16,       // [N, H*64] bf16
    float* __restrict__ a_s, float* __restrict__ a_d,                // [N*H]
    int N) {
  int tid = threadIdx.x;
  int wave = tid >> 6, lane = tid & 63;
  int quad = lane >> 4, l16 = lane & 15;
  int n0 = blockIdx.x * 64;
  int head = blockIdx.y;
  int m0 = head * 64;
  const int M = H * 64;

  f32x4 acc[4];
#pragma unroll
  for (int t = 0; t < 4; ++t) acc[t] = (f32x4){0.f, 0.f, 0.f, 0.f};

  const ushort_t* Ap = Ab + (size_t)(n0 + wave * 16 + l16) * K + quad * 8;
  const ushort_t* Wp = WT + (size_t)(m0 + l16) * K + quad * 8;

  for (int k0 = 0; k0 < K; k0 += 32) {
    bf16x8 af = *(const bf16x8*)(Ap + k0);
#pragma unroll
    for (int t = 0; t < 4; ++t) {
      bf16x8 bf = *(const bf16x8*)(Wp + (size_t)t * 16 * K + k0);
      acc[t] = __builtin_amdgcn_mfma_f32_16x16x32_bf16(af, bf, acc[t], 0, 0, 0);
    }
  }

#pragma unroll
  for (int reg = 0; reg < 4; ++reg) {
    int r = n0 + wave * 16 + quad * 4 + reg;
    float ps = 0.f, pd = 0.f;
#pragma unroll
    for (int t = 0; t < 4; ++t) {
      float v = acc[t][reg];
      int col = m0 + t * 16 + l16;
      ps = fmaf(v, atts[col], ps);
      pd = fmaf(v, attd[col], pd);
      if (r < N) hb16[(size_t)r * M + col] = f2b(v);
    }
#pragma unroll
    for (int off = 8; off; off >>= 1) {
      ps += __shfl_xor(ps, off);
      pd += __shfl_xor(pd, off);
    }
    if (l16 == 0 && r < N) {
      a_s[r * H + head] = ps;
      a_d[r * H + head] = pd;
    }
  }
}

// ---------- pair-gather core: two edges per wave-instruction, u32 (2 cols) per lane ----------
__device__ __forceinline__ void pair_gather(const char* hbase, float alpha, int offb,
                                            int deg, float& acc0, float& acc1) {
  int half = (threadIdx.x & 63) >> 5;
  int t = 0;
  for (; t + 4 <= deg; t += 4) {
    float a01 = half ? bcast_f(alpha, t + 1) : bcast_f(alpha, t);
    int o01 = half ? bcast_i(offb, t + 1) : bcast_i(offb, t);
    float a23 = half ? bcast_f(alpha, t + 3) : bcast_f(alpha, t + 2);
    int o23 = half ? bcast_i(offb, t + 3) : bcast_i(offb, t + 2);
    unsigned u0 = *(const unsigned*)(hbase + o01);
    unsigned u1 = *(const unsigned*)(hbase + o23);
    acc0 = fmaf(a01, __uint_as_float(u0 << 16), acc0);
    acc1 = fmaf(a01, __uint_as_float(u0 & 0xffff0000u), acc1);
    acc0 = fmaf(a23, __uint_as_float(u1 << 16), acc0);
    acc1 = fmaf(a23, __uint_as_float(u1 & 0xffff0000u), acc1);
  }
  for (; t < deg; t += 2) {
    int t1 = t + 1;  // alpha[t1]==0 when t1>=deg (and t1<=63 since deg<=64)
    float av = half ? bcast_f(alpha, t1) : bcast_f(alpha, t);
    int ob = half ? bcast_i(offb, t1) : bcast_i(offb, t);
    unsigned u = *(const unsigned*)(hbase + ob);
    acc0 = fmaf(av, __uint_as_float(u << 16), acc0);
    acc1 = fmaf(av, __uint_as_float(u & 0xffff0000u), acc1);
  }
}

// ---------- fused aggregation, layers 0/1 (H=4, C=64): softmax + gather + bias+ELU+BN ----------
__global__ __launch_bounds__(256) void aggregate_kernel(
    const ushort_t* __restrict__ hb16, const float* __restrict__ a_s,
    const float* __restrict__ a_d,
    const int* __restrict__ row_ptr, const int* __restrict__ srcs,
    const float* __restrict__ bias, const float* __restrict__ gam, const float* __restrict__ bet,
    const float* __restrict__ rmean, const float* __restrict__ rvar,
    ushort_t* __restrict__ xb16, int N) {
  int n = blockIdx.x;
  int hh = threadIdx.x >> 6;
  int lane = threadIdx.x & 63;
  int half = lane >> 5;
  int c2 = (lane & 31) << 1;  // this lane's column pair
  int jb = row_ptr[n], je = row_ptr[n + 1];
  int deg = je - jb;
  float adn = a_d[n * 4 + hh];
  const char* hbase = (const char*)hb16 + hh * 128 + c2 * 2;
  float acc0 = 0.f, acc1 = 0.f;

  if (deg <= 64) {
    int s = (lane < deg) ? srcs[jb + lane] : 0;
    float l = (lane < deg) ? lrelu(a_s[s * 4 + hh] + adn) : -1e30f;
    float mx = l;
#pragma unroll
    for (int off = 32; off; off >>= 1) mx = fmaxf(mx, __shfl_xor(mx, off));
    float e = (lane < deg) ? __expf(l - mx) : 0.f;
    float sum = e;
#pragma unroll
    for (int off = 32; off; off >>= 1) sum += __shfl_xor(sum, off);
    float alpha = e / (sum + 1e-16f);
    int offb = s * 512;  // bf16 row stride = 256*2 bytes
    pair_gather(hbase, alpha, offb, deg, acc0, acc1);
  } else {
    float mx = -1e30f;
    for (int j = jb + lane; j < je; j += 64)
      mx = fmaxf(mx, lrelu(a_s[srcs[j] * 4 + hh] + adn));
#pragma unroll
    for (int off = 32; off; off >>= 1) mx = fmaxf(mx, __shfl_xor(mx, off));
    float sum = 0.f;
    for (int j = jb + lane; j < je; j += 64)
      sum += __expf(lrelu(a_s[srcs[j] * 4 + hh] + adn) - mx);
#pragma unroll
    for (int off = 32; off; off >>= 1) sum += __shfl_xor(sum, off);
    float inv = 1.0f / (sum + 1e-16f);
    for (int j0 = jb; j0 < je; j0 += 64) {
      int cnt = min(64, je - j0);
      int s = (lane < cnt) ? srcs[j0 + lane] : 0;
      float alpha = (lane < cnt) ? __expf(lrelu(a_s[s * 4 + hh] + adn) - mx) * inv : 0.f;
      int offb = s * 512;
      pair_gather(hbase, alpha, offb, cnt, acc0, acc1);
    }
  }

  acc0 += __shfl_xor(acc0, 32);
  acc1 += __shfl_xor(acc1, 32);

  if (half == 0) {
    int col = hh * 64 + c2;
    float2 bi = *(const float2*)&bias[col];
    float2 gm = *(const float2*)&gam[col];
    float2 bt = *(const float2*)&bet[col];
    float2 rm = *(const float2*)&rmean[col];
    float2 rv = *(const float2*)&rvar[col];
    float v0 = acc0 + bi.x, v1 = acc1 + bi.y;
    v0 = v0 > 0.f ? v0 : (__expf(v0) - 1.f);
    v1 = v1 > 0.f ? v1 : (__expf(v1) - 1.f);
    v0 = fmaf(gm.x * (v0 - rm.x), rsqrtf(rv.x + 1e-5f), bt.x);
    v1 = fmaf(gm.y * (v1 - rm.y), rsqrtf(rv.y + 1e-5f), bt.y);
    unsigned pk = (unsigned)f2b(v0) | ((unsigned)f2b(v1) << 16);
    *(unsigned*)((char*)xb16 + (size_t)n * 512 + col * 2) = pk;
  }
}

// ---------- fused aggregation layer 2 (H=1, C=64) + bias + log_softmax ----------
__global__ __launch_bounds__(256) void aggregate2_kernel(
    const ushort_t* __restrict__ hb16, const float* __restrict__ a_s,
    const float* __restrict__ a_d,
    const int* __restrict__ row_ptr, const int* __restrict__ srcs,
    const float* __restrict__ bias, float* __restrict__ out, int N) {
  int n = blockIdx.x * 4 + (threadIdx.x >> 6);
  int lane = threadIdx.x & 63;
  int half = lane >> 5;
  int c2 = (lane & 31) << 1;
  if (n >= N) return;
  int jb = row_ptr[n], je = row_ptr[n + 1];
  int deg = je - jb;
  float adn = a_d[n];
  const char* hbase = (const char*)hb16 + c2 * 2;
  float acc0 = 0.f, acc1 = 0.f;

  if (deg <= 64) {
    int s = (lane < deg) ? srcs[jb + lane] : 0;
    float l = (lane < deg) ? lrelu(a_s[s] + adn) : -1e30f;
    float mx = l;
#pragma unroll
    for (int off = 32; off; off >>= 1) mx = fmaxf(mx, __shfl_xor(mx, off));
    float e = (lane < deg) ? __expf(l - mx) : 0.f;
    float sum = e;
#pragma unroll
    for (int off = 32; off; off >>= 1) sum += __shfl_xor(sum, off);
    float alpha = e / (sum + 1e-16f);
    int offb = s * 128;  // bf16 row stride = 64*2 bytes
    pair_gather(hbase, alpha, offb, deg, acc0, acc1);
  } else {
    float mx = -1e30f;
    for (int j = jb + lane; j < je; j += 64)
      mx = fmaxf(mx, lrelu(a_s[srcs[j]] + adn));
#pragma unroll
    for (int off = 32; off; off >>= 1) mx = fmaxf(mx, __shfl_xor(mx, off));
    float sum = 0.f;
    for (int j = jb + lane; j < je; j += 64)
      sum += __expf(lrelu(a_s[srcs[j]] + adn) - mx);
#pragma unroll
    for (int off = 32; off; off >>= 1) sum += __shfl_xor(sum, off);
    float inv = 1.0f / (sum + 1e-16f);
    for (int j0 = jb; j0 < je; j0 += 64) {
      int cnt = min(64, je - j0);
      int s = (lane < cnt) ? srcs[j0 + lane] : 0;
      float alpha = (lane < cnt) ? __expf(lrelu(a_s[s] + adn) - mx) * inv : 0.f;
      int offb = s * 128;
      pair_gather(hbase, alpha, offb, cnt, acc0, acc1);
    }
  }

  acc0 += __shfl_xor(acc0, 32);
  acc1 += __shfl_xor(acc1, 32);

  float2 bi = *(const float2*)&bias[c2];
  float v0 = acc0 + bi.x, v1 = acc1 + bi.y;
  // log-softmax over the 64 cols (both halves hold mirrored values; reduce within 32)
  float mx = fmaxf(v0, v1);
#pragma unroll
  for (int off = 16; off; off >>= 1) mx = fmaxf(mx, __shfl_xor(mx, off));
  float ex = __expf(v0 - mx) + __expf(v1 - mx);
#pragma unroll
  for (int off = 16; off; off >>= 1) ex += __shfl_xor(ex, off);
  float lse = mx + logf(ex);
  if (half == 0) {
    float2 o = make_float2(v0 - lse, v1 - lse);
    *(float2*)&out[(size_t)n * 64 + c2] = o;
  }
}

// ---------- host ----------
extern "C" void kernel_launch(void* const* d_in, const int* in_sizes, int n_in,
                              void* d_out, int out_size, void* d_ws, size_t ws_size,
                              hipStream_t stream) {
  const float* x = (const float*)d_in[0];
  const int* ei = (const int*)d_in[1];
  const float* W0 = (const float*)d_in[2];
  const float* as0 = (const float*)d_in[3];
  const float* ad0 = (const float*)d_in[4];
  const float* b0 = (const float*)d_in[5];
  const float* g0p = (const float*)d_in[6];
  const float* be0 = (const float*)d_in[7];
  const float* m0p = (const float*)d_in[8];
  const float* v0p = (const float*)d_in[9];
  const float* W1 = (const float*)d_in[10];
  const float* as1 = (const float*)d_in[11];
  const float* ad1 = (const float*)d_in[12];
  const float* b1 = (const float*)d_in[13];
  const float* g1p = (const float*)d_in[14];
  const float* be1 = (const float*)d_in[15];
  const float* m1p = (const float*)d_in[16];
  const float* v1p = (const float*)d_in[17];
  const float* W2 = (const float*)d_in[18];
  const float* as2 = (const float*)d_in[19];
  const float* ad2 = (const float*)d_in[20];
  const float* b2 = (const float*)d_in[21];
  float* out = (float*)d_out;

  const int N = NNODES;
  char* p = (char*)d_ws;
  auto alloc = [&](size_t bytes) {
    void* r = (void*)p;
    p += (bytes + 255) & ~(size_t)255;
    return r;
  };
  ushort_t* xb0 = (ushort_t*)alloc((size_t)NPAD * 128 * 2);   // layer-0 input, bf16
  ushort_t* xb16 = (ushort_t*)alloc((size_t)NPAD * 256 * 2);  // layer-1/2 input, bf16
  ushort_t* hb16 = (ushort_t*)alloc((size_t)N * 256 * 2);     // per-layer h, bf16
  ushort_t* WT0 = (ushort_t*)alloc((size_t)256 * 128 * 2);
  ushort_t* WT1 = (ushort_t*)alloc((size_t)256 * 256 * 2);
  ushort_t* WT2 = (ushort_t*)alloc((size_t)64 * 256 * 2);
  float* a_s = (float*)alloc((size_t)N * 4 * 4);
  float* a_d = (float*)alloc((size_t)N * 4 * 4);
  int* counts = (int*)alloc((size_t)N * 4);
  int* row_ptr = (int*)alloc((size_t)(N + 1) * 4);
  int* cursor = (int*)alloc((size_t)N * 4);
  int* srcs = (int*)alloc((size_t)NTOT * 4);

  // zero histogram bins, then one fused prep kernel (conversions + histogram)
  hipMemsetAsync(counts, 0, (size_t)N * 4, stream);
  prep_kernel<<<BX + BW0 + BW1 + BW2 + BH, 256, 0, stream>>>(
      x, W0, W1, W2, ei, xb0, WT0, WT1, WT2, counts);
  scan_kernel<<<1, 256, 0, stream>>>(counts, row_ptr, cursor, srcs);
  scatter_kernel<<<BH, 256, 0, stream>>>(ei, cursor, srcs);

  dim3 gblk(256);
  // ---- layer 0 ----
  gemm_att_kernel<128, 4><<<dim3(NPAD / 64, 4), gblk, 0, stream>>>(
      xb0, WT0, as0, ad0, hb16, a_s, a_d, N);
  aggregate_kernel<<<N, 256, 0, stream>>>(hb16, a_s, a_d, row_ptr, srcs,
                                          b0, g0p, be0, m0p, v0p, xb16, N);
  // ---- layer 1 ----
  gemm_att_kernel<256, 4><<<dim3(NPAD / 64, 4), gblk, 0, stream>>>(
      xb16, WT1, as1, ad1, hb16, a_s, a_d, N);
  aggregate_kernel<<<N, 256, 0, stream>>>(hb16, a_s, a_d, row_ptr, srcs,
                                          b1, g1p, be1, m1p, v1p, xb16, N);
  // ---- layer 2 ----
  gemm_att_kernel<256, 1><<<dim3(NPAD / 64, 1), gblk, 0, stream>>>(
      xb16, WT2, as2, ad2, hb16, a_s, a_d, N);
  aggregate2_kernel<<<(N + 3) / 4, 256, 0, stream>>>(hb16, a_s, a_d,
                                                     row_ptr, srcs, b2, out, N);
}